// Round 11
// baseline (82.053 us; speedup 1.0000x reference)
//
#include <hip/hip_runtime.h>

// GraphConsis fused encoder + dot — round 10.
// B=4096, H=50, A=32, L=82, D=64, tables 100000x64 f32.
//
// Clean test of the per-TRANSACTION service model: R7's 8-rows-per-VMEM
// f16 main kernel (11 gather transactions/wave vs 21) was polluted by its
// conversion kernel's scalar 2B stores (dirty L2 -> 53MB writeback during
// main). This round: conversion with NT loads AND 16B NT stores (no dirty
// lines), then the 8-row main.
//   model A (transaction-limited): main ~28-35us, total ~42-48us
//   model B (latency/byte-mixed):  main ~45-51us, total neutral -> roofline,
//                                  revert to R9 f32 single-dispatch.

typedef _Float16 half8v __attribute__((ext_vector_type(8)));
typedef _Float16 half4v __attribute__((ext_vector_type(4)));
typedef float f32x4 __attribute__((ext_vector_type(4)));

#define NB 4096
#define NH 50
#define NA 32
#define ND 64
#define NROWS 100000

// ------- conversion: NT load + NT 16B store, both tables, one kernel -------

__global__ __launch_bounds__(256) void convert_f16_both(
    const float* __restrict__ u2e, const float* __restrict__ v2e,
    _Float16* __restrict__ uh, _Float16* __restrict__ vh, int n8_per)
{
    int i = blockIdx.x * blockDim.x + threadIdx.x;
    const int stride = gridDim.x * blockDim.x;
    const f32x4* su = (const f32x4*)u2e;
    const f32x4* sv = (const f32x4*)v2e;
    half8v* du = (half8v*)uh;
    half8v* dv = (half8v*)vh;
    for (; i < 2 * n8_per; i += stride) {
        const bool second = (i >= n8_per);
        const f32x4* s = second ? sv : su;
        half8v* d = second ? dv : du;
        const int k = second ? (i - n8_per) : i;
        const f32x4 a = __builtin_nontemporal_load(&s[2 * k]);
        const f32x4 c = __builtin_nontemporal_load(&s[2 * k + 1]);
        half8v h;
        h[0] = (_Float16)a.x; h[1] = (_Float16)a.y;
        h[2] = (_Float16)a.z; h[3] = (_Float16)a.w;
        h[4] = (_Float16)c.x; h[5] = (_Float16)c.y;
        h[6] = (_Float16)c.z; h[7] = (_Float16)c.w;
        __builtin_nontemporal_store(h, &d[k]);
    }
}

// ---------------- main kernel, f16 gather, 8 rows / transaction ----------

__global__ __launch_bounds__(256, 5) void graphconsis_f16(
    const float* __restrict__ u2e, const float* __restrict__ v2e,
    const _Float16* __restrict__ uh, const _Float16* __restrict__ vh,
    const float* __restrict__ r2e, const float* __restrict__ ra,
    const float* __restrict__ lin1_W, const float* __restrict__ lin1_b,
    const int* __restrict__ nodes_u, const int* __restrict__ nodes_v,
    const int* __restrict__ hist_u, const int* __restrict__ hist_ur,
    const int* __restrict__ adj_u,
    const int* __restrict__ hist_v, const int* __restrict__ hist_vr,
    const int* __restrict__ adj_v,
    float* __restrict__ out)
{
    __shared__ float lds_comb[4][128];
    __shared__ float ed[4][64];

    const int wid  = threadIdx.x >> 6;
    const int lane = threadIdx.x & 63;
    const int g    = lane >> 3;          // entry subgroup 0..7
    const int j    = lane & 7;           // dim-octet index 0..7
    const int side = wid >> 1;           // 0 = user, 1 = item
    const int b    = __builtin_amdgcn_readfirstlane(blockIdx.x * 2 + (wid & 1));

    const float* nodeTab     = side ? v2e : u2e;
    const _Float16* histTab  = side ? uh : vh;
    const _Float16* neighTab = side ? vh : uh;
    const int* nodes = side ? nodes_v : nodes_u;
    const int* hn    = side ? hist_v  : hist_u;
    const int* hr    = side ? hist_vr : hist_ur;
    const int* adj   = side ? adj_v   : adj_u;

    // per-lane dim octet of relation_att (low half)
    const float4 raA = *(const float4*)(ra + 8 * j);
    const float4 raB = *(const float4*)(ra + 8 * j + 4);

    // ---- index preload (entry 8k+g at iteration k) ----
    int hidx[7];
    #pragma unroll
    for (int k = 0; k < 7; ++k) {
        int l = 8 * k + g; if (l > NH - 1) l = NH - 1;
        hidx[k] = hn[b * NH + l];
    }
    int aidx[4];
    #pragma unroll
    for (int k = 0; k < 4; ++k)
        aidx[k] = adj[b * NA + 8 * k + g];
    int hrv = 6;   // rate idx for hist entry 8j+g (consumed at iter k==j, j<7)
    { int l = 8 * j + g; if (l < NH) hrv = hr[b * NH + l]; }

    // node row (f32): 16 lanes x float4; duplicated across lane>=16 (L1 hits)
    const float4 nf4 = *(const float4*)(nodeTab + nodes[b] * ND + 4 * (lane & 15));

    // ---- prefetch ALL embedding rows (11 transactions, 8 rows each) ----
    half8v rh[7];
    #pragma unroll
    for (int k = 0; k < 7; ++k)
        rh[k] = *(const half8v*)(histTab + hidx[k] * ND + 8 * j);
    half8v raj[4];
    #pragma unroll
    for (int k = 0; k < 4; ++k)
        raj[k] = *(const half8v*)(neighTab + aidx[k] * ND + 8 * j);

    // ---- per-wave rate logits (in-register; overlaps the gathers) ----
    const float ra_hi = ra[64 + lane];
    float r0, r1, r2, r3, r4, r5, r6;
    {
        float t[7];
        #pragma unroll
        for (int r = 0; r < 7; ++r) {
            float part = r2e[r * 64 + lane] * ra_hi;
            part += __shfl_xor(part, 1);
            part += __shfl_xor(part, 2);
            part += __shfl_xor(part, 4);
            part += __shfl_xor(part, 8);
            part += __shfl_xor(part, 16);
            part += __shfl_xor(part, 32);
            t[r] = part;
        }
        r0 = t[0]; r1 = t[1]; r2 = t[2]; r3 = t[3]; r4 = t[4]; r5 = t[5]; r6 = t[6];
    }
    float rl0 = r6;
    rl0 = (hrv == 0) ? r0 : rl0;
    rl0 = (hrv == 1) ? r1 : rl0;
    rl0 = (hrv == 2) ? r2 : rl0;
    rl0 = (hrv == 3) ? r3 : rl0;
    rl0 = (hrv == 4) ? r4 : rl0;
    rl0 = (hrv == 5) ? r5 : rl0;
    const float rlog6 = r6;

    float ssum = 0.f;
    float acc0 = 0.f, acc1 = 0.f, acc2 = 0.f, acc3 = 0.f;
    float acc4 = 0.f, acc5 = 0.f, acc6 = 0.f, acc7 = 0.f;

    // ---- history entries 0..47 (6 iters x 8 entries) ----
    #pragma unroll
    for (int k = 0; k < 6; ++k) {
        const half8v eh = rh[k];
        const float e0 = (float)eh[0], e1 = (float)eh[1], e2 = (float)eh[2], e3 = (float)eh[3];
        const float e4 = (float)eh[4], e5 = (float)eh[5], e6 = (float)eh[6], e7 = (float)eh[7];
        float part = e0 * raA.x;
        part = fmaf(e1, raA.y, part);
        part = fmaf(e2, raA.z, part);
        part = fmaf(e3, raA.w, part);
        part = fmaf(e4, raB.x, part);
        part = fmaf(e5, raB.y, part);
        part = fmaf(e6, raB.z, part);
        part = fmaf(e7, raB.w, part);
        part += (j == k) ? rl0 : 0.f;
        part += __shfl_xor(part, 1);
        part += __shfl_xor(part, 2);
        part += __shfl_xor(part, 4);
        const float p = __expf(part);
        ssum += p;
        acc0 = fmaf(p, e0, acc0); acc1 = fmaf(p, e1, acc1);
        acc2 = fmaf(p, e2, acc2); acc3 = fmaf(p, e3, acc3);
        acc4 = fmaf(p, e4, acc4); acc5 = fmaf(p, e5, acc5);
        acc6 = fmaf(p, e6, acc6); acc7 = fmaf(p, e7, acc7);
    }
    // ---- history tail: entries 48,49 live on groups 0,1 (k==6) ----
    {
        const half8v eh = rh[6];
        const float e0 = (float)eh[0], e1 = (float)eh[1], e2 = (float)eh[2], e3 = (float)eh[3];
        const float e4 = (float)eh[4], e5 = (float)eh[5], e6 = (float)eh[6], e7 = (float)eh[7];
        float part = e0 * raA.x;
        part = fmaf(e1, raA.y, part);
        part = fmaf(e2, raA.z, part);
        part = fmaf(e3, raA.w, part);
        part = fmaf(e4, raB.x, part);
        part = fmaf(e5, raB.y, part);
        part = fmaf(e6, raB.z, part);
        part = fmaf(e7, raB.w, part);
        part += (j == 6) ? rl0 : 0.f;
        part += __shfl_xor(part, 1);
        part += __shfl_xor(part, 2);
        part += __shfl_xor(part, 4);
        const float p = (g < 2) ? __expf(part) : 0.f;
        ssum += p;
        acc0 = fmaf(p, e0, acc0); acc1 = fmaf(p, e1, acc1);
        acc2 = fmaf(p, e2, acc2); acc3 = fmaf(p, e3, acc3);
        acc4 = fmaf(p, e4, acc4); acc5 = fmaf(p, e5, acc5);
        acc6 = fmaf(p, e6, acc6); acc7 = fmaf(p, e7, acc7);
    }
    // ---- adj entries 0..31 (4 iters x 8 entries), rate logit = rlog6 ----
    #pragma unroll
    for (int k = 0; k < 4; ++k) {
        const half8v eh = raj[k];
        const float e0 = (float)eh[0], e1 = (float)eh[1], e2 = (float)eh[2], e3 = (float)eh[3];
        const float e4 = (float)eh[4], e5 = (float)eh[5], e6 = (float)eh[6], e7 = (float)eh[7];
        float part = e0 * raA.x;
        part = fmaf(e1, raA.y, part);
        part = fmaf(e2, raA.z, part);
        part = fmaf(e3, raA.w, part);
        part = fmaf(e4, raB.x, part);
        part = fmaf(e5, raB.y, part);
        part = fmaf(e6, raB.z, part);
        part = fmaf(e7, raB.w, part);
        part += __shfl_xor(part, 1);
        part += __shfl_xor(part, 2);
        part += __shfl_xor(part, 4);
        const float p = __expf(part + rlog6);
        ssum += p;
        acc0 = fmaf(p, e0, acc0); acc1 = fmaf(p, e1, acc1);
        acc2 = fmaf(p, e2, acc2); acc3 = fmaf(p, e3, acc3);
        acc4 = fmaf(p, e4, acc4); acc5 = fmaf(p, e5, acc5);
        acc6 = fmaf(p, e6, acc6); acc7 = fmaf(p, e7, acc7);
    }

    // ---- combine the 8 entry-groups (xor over lane bits 3,4,5) ----
    #pragma unroll
    for (int off = 8; off <= 32; off <<= 1) {
        ssum += __shfl_xor(ssum, off);
        acc0 += __shfl_xor(acc0, off); acc1 += __shfl_xor(acc1, off);
        acc2 += __shfl_xor(acc2, off); acc3 += __shfl_xor(acc3, off);
        acc4 += __shfl_xor(acc4, off); acc5 += __shfl_xor(acc5, off);
        acc6 += __shfl_xor(acc6, off); acc7 += __shfl_xor(acc7, off);
    }
    const float inv = 1.0f / ssum;

    // ---- comb -> own LDS slice (wave-local, wave-synchronous) ----
    if (lane < 16)
        *(float4*)&lds_comb[wid][4 * lane] = nf4;   // nf dims 4*lane..
    if (g == 0) {                                    // lanes 0..7: neigh octet
        float4 nA = make_float4(acc0 * inv, acc1 * inv, acc2 * inv, acc3 * inv);
        float4 nB = make_float4(acc4 * inv, acc5 * inv, acc6 * inv, acc7 * inv);
        *(float4*)&lds_comb[wid][64 + 8 * j]     = nA;
        *(float4*)&lds_comb[wid][64 + 8 * j + 4] = nB;
    }

    // out_j = relu(b_j + sum_k W[j][k] * comb[k]); lane = output j
    float o = lin1_b[lane];
    const float4* W4 = (const float4*)(lin1_W + lane * 128);
    const float4* C4 = (const float4*)lds_comb[wid];
    #pragma unroll 8
    for (int kk = 0; kk < 32; ++kk) {
        const float4 w = W4[kk];
        const float4 c = C4[kk];
        o = fmaf(w.x, c.x, o);
        o = fmaf(w.y, c.y, o);
        o = fmaf(w.z, c.z, o);
        o = fmaf(w.w, c.w, o);
    }
    const float evec = fmaxf(o, 0.f);

    ed[wid][lane] = evec;
    __syncthreads();

    if (wid < 2) {
        float prod = ed[wid][lane] * ed[wid + 2][lane];
        #pragma unroll
        for (int off = 32; off >= 1; off >>= 1)
            prod += __shfl_xor(prod, off);
        if (lane == 0) out[blockIdx.x * 2 + wid] = prod;
    }
}

// ---------------- fallback f32 main kernel (round-8 proven) ----------------

__global__ __launch_bounds__(256, 4) void graphconsis_f32(
    const float* __restrict__ u2e, const float* __restrict__ v2e,
    const float* __restrict__ r2e, const float* __restrict__ ra,
    const float* __restrict__ lin1_W, const float* __restrict__ lin1_b,
    const int* __restrict__ nodes_u, const int* __restrict__ nodes_v,
    const int* __restrict__ hist_u, const int* __restrict__ hist_ur,
    const int* __restrict__ adj_u,
    const int* __restrict__ hist_v, const int* __restrict__ hist_vr,
    const int* __restrict__ adj_v,
    float* __restrict__ out)
{
    __shared__ float lds_comb[4][128];
    __shared__ float ed[4][64];

    const int wid  = threadIdx.x >> 6;
    const int lane = threadIdx.x & 63;
    const int g    = lane >> 4;
    const int j    = lane & 15;
    const int side = wid >> 1;
    const int b    = __builtin_amdgcn_readfirstlane(blockIdx.x * 2 + (wid & 1));

    const float* nodeTab  = side ? v2e : u2e;
    const float* histTab  = side ? u2e : v2e;
    const float* neighTab = side ? v2e : u2e;
    const int* nodes = side ? nodes_v : nodes_u;
    const int* hn    = side ? hist_v  : hist_u;
    const int* hr    = side ? hist_vr : hist_ur;
    const int* adj   = side ? adj_v   : adj_u;

    const float4 ra4 = *(const float4*)(ra + 4 * j);

    const int lcl  = (lane < NH) ? lane : NH - 1;
    const int hraw = hn[b * NH + lcl];
    const int rraw = hr[b * NH + lcl];
    const int araw = adj[b * NA + (lane & 31)];

    int hidx[13];
    #pragma unroll
    for (int k = 0; k < 13; ++k) {
        int l = 4 * k + g; if (l > NH - 1) l = NH - 1;
        hidx[k] = __shfl(hraw, l);
    }
    int aidx[8];
    #pragma unroll
    for (int k = 0; k < 8; ++k)
        aidx[k] = __shfl(araw, 4 * k + g);
    const int hrv = __shfl(rraw, (4 * j + g < NH) ? (4 * j + g) : NH - 1);
    const bool hrv_valid = (4 * j + g) < NH;

    const float4 nf4 = *(const float4*)(nodeTab + nodes[b] * ND + 4 * j);
    float4 rh[13];
    #pragma unroll
    for (int k = 0; k < 13; ++k)
        rh[k] = *(const float4*)(histTab + hidx[k] * ND + 4 * j);
    float4 raj[8];
    #pragma unroll
    for (int k = 0; k < 8; ++k)
        raj[k] = *(const float4*)(neighTab + aidx[k] * ND + 4 * j);

    const float ra_hi = ra[64 + lane];
    float r0, r1, r2, r3, r4, r5, r6;
    {
        float t[7];
        #pragma unroll
        for (int r = 0; r < 7; ++r) {
            float part = r2e[r * 64 + lane] * ra_hi;
            part += __shfl_xor(part, 1);
            part += __shfl_xor(part, 2);
            part += __shfl_xor(part, 4);
            part += __shfl_xor(part, 8);
            part += __shfl_xor(part, 16);
            part += __shfl_xor(part, 32);
            t[r] = part;
        }
        r0 = t[0]; r1 = t[1]; r2 = t[2]; r3 = t[3]; r4 = t[4]; r5 = t[5]; r6 = t[6];
    }
    float rl0 = r6;
    rl0 = (hrv == 0) ? r0 : rl0;
    rl0 = (hrv == 1) ? r1 : rl0;
    rl0 = (hrv == 2) ? r2 : rl0;
    rl0 = (hrv == 3) ? r3 : rl0;
    rl0 = (hrv == 4) ? r4 : rl0;
    rl0 = (hrv == 5) ? r5 : rl0;
    rl0 = hrv_valid ? rl0 : r6;
    const float rlog6 = r6;

    float ssum = 0.f;
    float4 acc = make_float4(0.f, 0.f, 0.f, 0.f);

    #pragma unroll
    for (int k = 0; k < 12; ++k) {
        const float4 e = rh[k];
        float part = e.x * ra4.x;
        part = fmaf(e.y, ra4.y, part);
        part = fmaf(e.z, ra4.z, part);
        part = fmaf(e.w, ra4.w, part);
        part += (j == k) ? rl0 : 0.f;
        part += __shfl_xor(part, 1);
        part += __shfl_xor(part, 2);
        part += __shfl_xor(part, 4);
        part += __shfl_xor(part, 8);
        const float p = __expf(part);
        ssum += p;
        acc.x = fmaf(p, e.x, acc.x);
        acc.y = fmaf(p, e.y, acc.y);
        acc.z = fmaf(p, e.z, acc.z);
        acc.w = fmaf(p, e.w, acc.w);
    }
    {
        const float4 e = rh[12];
        float part = e.x * ra4.x;
        part = fmaf(e.y, ra4.y, part);
        part = fmaf(e.z, ra4.z, part);
        part = fmaf(e.w, ra4.w, part);
        part += (j == 12) ? rl0 : 0.f;
        part += __shfl_xor(part, 1);
        part += __shfl_xor(part, 2);
        part += __shfl_xor(part, 4);
        part += __shfl_xor(part, 8);
        const float p = (g < 2) ? __expf(part) : 0.f;
        ssum += p;
        acc.x = fmaf(p, e.x, acc.x);
        acc.y = fmaf(p, e.y, acc.y);
        acc.z = fmaf(p, e.z, acc.z);
        acc.w = fmaf(p, e.w, acc.w);
    }
    #pragma unroll
    for (int k = 0; k < 8; ++k) {
        const float4 e = raj[k];
        float part = e.x * ra4.x;
        part = fmaf(e.y, ra4.y, part);
        part = fmaf(e.z, ra4.z, part);
        part = fmaf(e.w, ra4.w, part);
        part += __shfl_xor(part, 1);
        part += __shfl_xor(part, 2);
        part += __shfl_xor(part, 4);
        part += __shfl_xor(part, 8);
        const float p = __expf(part + rlog6);
        ssum += p;
        acc.x = fmaf(p, e.x, acc.x);
        acc.y = fmaf(p, e.y, acc.y);
        acc.z = fmaf(p, e.z, acc.z);
        acc.w = fmaf(p, e.w, acc.w);
    }

    ssum += __shfl_xor(ssum, 16);
    ssum += __shfl_xor(ssum, 32);
    acc.x += __shfl_xor(acc.x, 16); acc.x += __shfl_xor(acc.x, 32);
    acc.y += __shfl_xor(acc.y, 16); acc.y += __shfl_xor(acc.y, 32);
    acc.z += __shfl_xor(acc.z, 16); acc.z += __shfl_xor(acc.z, 32);
    acc.w += __shfl_xor(acc.w, 16); acc.w += __shfl_xor(acc.w, 32);

    const float inv = 1.0f / ssum;

    if (g == 0) {
        *(float4*)&lds_comb[wid][4 * j] = nf4;
        float4 n4 = make_float4(acc.x * inv, acc.y * inv, acc.z * inv, acc.w * inv);
        *(float4*)&lds_comb[wid][64 + 4 * j] = n4;
    }

    float o = lin1_b[lane];
    const float4* W4 = (const float4*)(lin1_W + lane * 128);
    const float4* C4 = (const float4*)lds_comb[wid];
    #pragma unroll 8
    for (int kk = 0; kk < 32; ++kk) {
        const float4 w = W4[kk];
        const float4 c = C4[kk];
        o = fmaf(w.x, c.x, o);
        o = fmaf(w.y, c.y, o);
        o = fmaf(w.z, c.z, o);
        o = fmaf(w.w, c.w, o);
    }
    const float evec = fmaxf(o, 0.f);

    ed[wid][lane] = evec;
    __syncthreads();

    if (wid < 2) {
        float prod = ed[wid][lane] * ed[wid + 2][lane];
        #pragma unroll
        for (int off = 32; off >= 1; off >>= 1)
            prod += __shfl_xor(prod, off);
        if (lane == 0) out[blockIdx.x * 2 + wid] = prod;
    }
}

// ---------------- launch ----------------

extern "C" void kernel_launch(void* const* d_in, const int* in_sizes, int n_in,
                              void* d_out, int out_size, void* d_ws, size_t ws_size,
                              hipStream_t stream)
{
    const float* u2e     = (const float*)d_in[0];
    const float* v2e     = (const float*)d_in[1];
    const float* r2e     = (const float*)d_in[2];
    const float* ra      = (const float*)d_in[3];
    // d_in[4] agg_W, d_in[5] agg_b: dead code in the reference
    const float* lin1_W  = (const float*)d_in[6];
    const float* lin1_b  = (const float*)d_in[7];
    const int* nodes_u   = (const int*)d_in[8];
    const int* nodes_v   = (const int*)d_in[9];
    const int* hist_u    = (const int*)d_in[10];
    const int* hist_ur   = (const int*)d_in[11];
    const int* adj_u     = (const int*)d_in[12];
    const int* hist_v    = (const int*)d_in[13];
    const int* hist_vr   = (const int*)d_in[14];
    const int* adj_v     = (const int*)d_in[15];
    float* out = (float*)d_out;

    const size_t tab_elems = (size_t)NROWS * ND;           // 6.4M
    const size_t f16_bytes = tab_elems * sizeof(_Float16); // 12.8MB per table
    const size_t need = 2 * f16_bytes;

    if (ws_size >= need) {
        _Float16* uh = (_Float16*)d_ws;
        _Float16* vh = (_Float16*)((char*)d_ws + f16_bytes);
        const int n8_per = (int)(tab_elems / 8);
        hipLaunchKernelGGL(convert_f16_both, dim3(2048), dim3(256), 0, stream,
                           u2e, v2e, uh, vh, n8_per);
        hipLaunchKernelGGL(graphconsis_f16, dim3(NB / 2), dim3(256), 0, stream,
                           u2e, v2e, uh, vh, r2e, ra, lin1_W, lin1_b,
                           nodes_u, nodes_v, hist_u, hist_ur, adj_u,
                           hist_v, hist_vr, adj_v, out);
    } else {
        hipLaunchKernelGGL(graphconsis_f32, dim3(NB / 2), dim3(256), 0, stream,
                           u2e, v2e, r2e, ra, lin1_W, lin1_b,
                           nodes_u, nodes_v, hist_u, hist_ur, adj_u,
                           hist_v, hist_vr, adj_v, out);
    }
}

// Round 12
// 55.899 us; speedup vs baseline: 1.4679x; 1.4679x over previous
//
#include <hip/hip_runtime.h>

// GraphConsis fused encoder + dot — round 11 = round 9 restored (best: 56.75us).
// B=4096, H=50, A=32, L=82, D=64, tables 100000x64 f32.
//
// Final model (fits R1-R10): scattered 256B-row gather service is pinned at
// ~1.5 TB/s by per-CU miss-tracking depth (~24-32 lines) x L3 latency
// (~600cy): 256CU x 28 x 64B / 600cy = 1.53 TB/s — invariant across
// occupancy, outstanding-load depth, dtype, lane width, and transaction
// count (7 structures, R1-R10). f16 halves bytes but costs a 13-18us
// conversion per call — net null. This kernel: f32 single-dispatch,
// global_load_lds 8-slot ring (VGPR-free staging), counted vmcnt waits,
// shuffle-distributed indices, in-register rlog, fused epilogue.

#define NB 4096
#define NH 50
#define NA 32
#define ND 64
#define SLOTS 8

typedef const __attribute__((address_space(1))) unsigned int* gld_src_t;
typedef __attribute__((address_space(3))) unsigned int* gld_dst_t;

__global__ __launch_bounds__(256) void graphconsis_main(
    const float* __restrict__ u2e, const float* __restrict__ v2e,
    const float* __restrict__ r2e, const float* __restrict__ ra,
    const float* __restrict__ lin1_W, const float* __restrict__ lin1_b,
    const int* __restrict__ nodes_u, const int* __restrict__ nodes_v,
    const int* __restrict__ hist_u, const int* __restrict__ hist_ur,
    const int* __restrict__ adj_u,
    const int* __restrict__ hist_v, const int* __restrict__ hist_vr,
    const int* __restrict__ adj_v,
    float* __restrict__ out)
{
    __shared__ __align__(16) float stage[4][SLOTS][256]; // 32KB: 8 slots/wave, 4 rows/slot
    __shared__ float lds_comb[4][128];
    __shared__ float ed[4][64];

    const int wid  = threadIdx.x >> 6;
    const int lane = threadIdx.x & 63;
    const int g    = lane >> 4;          // entry subgroup 0..3
    const int j    = lane & 15;          // dim-quad index
    const int side = wid >> 1;           // 0 = user, 1 = item
    const int b    = __builtin_amdgcn_readfirstlane(blockIdx.x * 2 + (wid & 1));

    const float* nodeTab  = side ? v2e : u2e;
    const float* histTab  = side ? u2e : v2e;
    const float* neighTab = side ? v2e : u2e;
    const int* nodes = side ? nodes_v : nodes_u;
    const int* hn    = side ? hist_v  : hist_u;
    const int* hr    = side ? hist_vr : hist_ur;
    const int* adj   = side ? adj_v   : adj_u;

    // ---- ALL auxiliary VMEM up front (drained before the counted ring) ----
    const float4 ra4  = *(const float4*)(ra + 4 * j);
    const float ra_hi = ra[64 + lane];

    const int lcl  = (lane < NH) ? lane : NH - 1;
    const int hraw = hn[b * NH + lcl];          // lane l: history index l
    const int rraw = hr[b * NH + lcl];          // lane l: rating of entry l
    const int araw = adj[b * NA + (lane & 31)]; // lane l: adj index l&31

    float r2v[7];
    #pragma unroll
    for (int r = 0; r < 7; ++r) r2v[r] = r2e[r * 64 + lane];

    // distribute indices to (g,k) layout: staged load k covers entries 4k+g
    int idx[21];
    #pragma unroll
    for (int k = 0; k < 13; ++k) {
        int l = 4 * k + g; if (l > NH - 1) l = NH - 1;   // entries 50,51 masked later
        idx[k] = __shfl(hraw, l);
    }
    #pragma unroll
    for (int k = 0; k < 8; ++k)
        idx[13 + k] = __shfl(araw, 4 * k + g);

    const int hrv = __shfl(rraw, (4 * j + g < NH) ? (4 * j + g) : NH - 1);

    // drain aux VMEM: vmcnt now counts ONLY staged loads
    asm volatile("s_waitcnt vmcnt(0)" ::: "memory");

    // ---- staged-load issue: 4 rows per instruction, no dest VGPRs ----
#define ISSUE(k) do {                                                          \
        const float* _s = (((k) < 13) ? histTab : neighTab)                    \
                          + (size_t)idx[(k)] * ND + 4 * j;                     \
        __builtin_amdgcn_global_load_lds((gld_src_t)(const void*)_s,           \
            (gld_dst_t)(void*)&stage[wid][(k) % SLOTS][0], 16, 0, 0);          \
    } while (0)

    // prologue: fill 7 of 8 slots
    #pragma unroll
    for (int k = 0; k < 7; ++k) ISSUE(k);

    // ---- rate logits in-register (shuffle-only; overlaps load flight) ----
    float t[7];
    #pragma unroll
    for (int r = 0; r < 7; ++r) {
        float part = r2v[r] * ra_hi;
        part += __shfl_xor(part, 1);
        part += __shfl_xor(part, 2);
        part += __shfl_xor(part, 4);
        part += __shfl_xor(part, 8);
        part += __shfl_xor(part, 16);
        part += __shfl_xor(part, 32);
        t[r] = part;
    }
    float rl0 = t[6];
    rl0 = (hrv == 0) ? t[0] : rl0;
    rl0 = (hrv == 1) ? t[1] : rl0;
    rl0 = (hrv == 2) ? t[2] : rl0;
    rl0 = (hrv == 3) ? t[3] : rl0;
    rl0 = (hrv == 4) ? t[4] : rl0;
    rl0 = (hrv == 5) ? t[5] : rl0;
    const float rlog6 = t[6];

    float ssum = 0.f;
    float4 acc = make_float4(0.f, 0.f, 0.f, 0.f);

    // ---- 21 steps: {lgkm guard; issue k+7; vmcnt(N); consume slot k%8} ----
    // N = 7 for k<=13 (issued-(k+1)), then 20-k.
#define STEP(k, N) do {                                                        \
        asm volatile("s_waitcnt lgkmcnt(0)" ::: "memory");                     \
        if ((k) + 7 < 21) { ISSUE((k) + 7); }                                  \
        asm volatile("s_waitcnt vmcnt(" #N ")" ::: "memory");                  \
        const float4 e = *(const float4*)&stage[wid][(k) % SLOTS][lane * 4];   \
        float part = e.x * ra4.x;                                              \
        part = fmaf(e.y, ra4.y, part);                                         \
        part = fmaf(e.z, ra4.z, part);                                         \
        part = fmaf(e.w, ra4.w, part);                                         \
        if ((k) < 13) part += (j == (k)) ? rl0 : 0.f;                          \
        part += __shfl_xor(part, 1);                                           \
        part += __shfl_xor(part, 2);                                           \
        part += __shfl_xor(part, 4);                                           \
        part += __shfl_xor(part, 8);                                           \
        if ((k) >= 13) part += rlog6;                                          \
        float p = __expf(part);                                                \
        if ((k) == 12) { if (g >= 2) p = 0.f; }                                \
        ssum += p;                                                             \
        acc.x = fmaf(p, e.x, acc.x);                                           \
        acc.y = fmaf(p, e.y, acc.y);                                           \
        acc.z = fmaf(p, e.z, acc.z);                                           \
        acc.w = fmaf(p, e.w, acc.w);                                           \
    } while (0);

    STEP(0, 7)  STEP(1, 7)  STEP(2, 7)  STEP(3, 7)  STEP(4, 7)
    STEP(5, 7)  STEP(6, 7)  STEP(7, 7)  STEP(8, 7)  STEP(9, 7)
    STEP(10, 7) STEP(11, 7) STEP(12, 7) STEP(13, 7)
    STEP(14, 6) STEP(15, 5) STEP(16, 4) STEP(17, 3)
    STEP(18, 2) STEP(19, 1) STEP(20, 0)

#undef STEP
#undef ISSUE

    // ---- combine the 4 entry-groups ----
    ssum += __shfl_xor(ssum, 16);
    ssum += __shfl_xor(ssum, 32);
    acc.x += __shfl_xor(acc.x, 16); acc.x += __shfl_xor(acc.x, 32);
    acc.y += __shfl_xor(acc.y, 16); acc.y += __shfl_xor(acc.y, 32);
    acc.z += __shfl_xor(acc.z, 16); acc.z += __shfl_xor(acc.z, 32);
    acc.w += __shfl_xor(acc.w, 16); acc.w += __shfl_xor(acc.w, 32);

    const float inv = 1.0f / ssum;

    // ---- epilogue VMEM (after last counted wait): node row ----
    const float4 nf4 = *(const float4*)(nodeTab + nodes[b] * ND + 4 * j);

    // comb -> own LDS slice (wave-local, wave-synchronous: no barrier)
    if (g == 0) {
        *(float4*)&lds_comb[wid][4 * j] = nf4;
        float4 n4 = make_float4(acc.x * inv, acc.y * inv, acc.z * inv, acc.w * inv);
        *(float4*)&lds_comb[wid][64 + 4 * j] = n4;
    }

    // out_j = relu(b_j + sum_k W[j][k] * comb[k]); lane = output j
    float o = lin1_b[lane];
    const float4* W4 = (const float4*)(lin1_W + lane * 128);
    const float4* C4 = (const float4*)lds_comb[wid];
    #pragma unroll 8
    for (int kk = 0; kk < 32; ++kk) {
        const float4 w = W4[kk];
        const float4 c = C4[kk];
        o = fmaf(w.x, c.x, o);
        o = fmaf(w.y, c.y, o);
        o = fmaf(w.z, c.z, o);
        o = fmaf(w.w, c.w, o);
    }
    const float evec = fmaxf(o, 0.f);

    ed[wid][lane] = evec;
    __syncthreads();

    if (wid < 2) {
        float prod = ed[wid][lane] * ed[wid + 2][lane];
        #pragma unroll
        for (int off = 32; off >= 1; off >>= 1)
            prod += __shfl_xor(prod, off);
        if (lane == 0) out[blockIdx.x * 2 + wid] = prod;
    }
}

extern "C" void kernel_launch(void* const* d_in, const int* in_sizes, int n_in,
                              void* d_out, int out_size, void* d_ws, size_t ws_size,
                              hipStream_t stream)
{
    const float* u2e     = (const float*)d_in[0];
    const float* v2e     = (const float*)d_in[1];
    const float* r2e     = (const float*)d_in[2];
    const float* ra      = (const float*)d_in[3];
    // d_in[4] agg_W, d_in[5] agg_b: dead code in the reference
    const float* lin1_W  = (const float*)d_in[6];
    const float* lin1_b  = (const float*)d_in[7];
    const int* nodes_u   = (const int*)d_in[8];
    const int* nodes_v   = (const int*)d_in[9];
    const int* hist_u    = (const int*)d_in[10];
    const int* hist_ur   = (const int*)d_in[11];
    const int* adj_u     = (const int*)d_in[12];
    const int* hist_v    = (const int*)d_in[13];
    const int* hist_vr   = (const int*)d_in[14];
    const int* adj_v     = (const int*)d_in[15];
    float* out = (float*)d_out;

    hipLaunchKernelGGL(graphconsis_main, dim3(NB / 2), dim3(256), 0, stream,
                       u2e, v2e, r2e, ra, lin1_W, lin1_b,
                       nodes_u, nodes_v, hist_u, hist_ur, adj_u,
                       hist_v, hist_vr, adj_v, out);
}